// Round 9
// baseline (347.784 us; speedup 1.0000x reference)
//
#include <hip/hip_runtime.h>
#include <hip/hip_bf16.h>
#include <stdint.h>

// MHA forward, fp32/bf16 in/out auto-detected, bf16 MFMA internal. MI355X gfx950.
// prep (W transpose, rope tab, x cvt; per-block dtype sniff) -> QKV GEMM (256x128 tile, +RoPE,
// Q pre-scaled, V transposed (B,H,d,S)) -> flash attn (S^T orientation) -> O-proj GEMM (128x128).
// gemm_bt<MODE,MT>: MT = # of 128-row m-tiles per block. BK=32 (BK=64 failed: occupancy cliff).

typedef __attribute__((ext_vector_type(8))) short short8;
typedef __attribute__((ext_vector_type(4))) float floatx4;
typedef __attribute__((ext_vector_type(16))) float floatx16;

#define MFMA16(a,b,c) __builtin_amdgcn_mfma_f32_16x16x32_bf16((a),(b),(c),0,0,0)
#define MFMA32(a,b,c) __builtin_amdgcn_mfma_f32_32x32x16_bf16((a),(b),(c),0,0,0)

__device__ __forceinline__ uint32_t fbits(float f){ uint32_t u; __builtin_memcpy(&u,&f,4); return u; }
__device__ __forceinline__ unsigned short f2bf(float f) {
    uint32_t u = fbits(f);
    return (unsigned short)((u + 0x7fffu + ((u>>16)&1u)) >> 16);
}
__device__ __forceinline__ float bf2f(unsigned short s){ uint32_t u = (uint32_t)s<<16; float f; __builtin_memcpy(&f,&u,4); return f; }
// pack two floats to bf16 pair (round-half-up), lo in low 16
__device__ __forceinline__ uint32_t pkbf(float lo, float hi) {
    return __builtin_amdgcn_perm(fbits(hi)+0x8000u, fbits(lo)+0x8000u, 0x07060302u);
}

__device__ __forceinline__ void load_lds16(const unsigned short* g, unsigned short* l) {
    __builtin_amdgcn_global_load_lds(
        (const __attribute__((address_space(1))) void*)g,
        (__attribute__((address_space(3))) void*)l, 16, 0, 0);
}

// wave-local dtype sniff: reinterpret first 1024 shorts of x as bf16; fp32 source shows
// huge/NaN patterns in mantissa halves with overwhelming probability. Deterministic ->
// every wave computes the same value; no cross-wave sync needed.
__device__ __forceinline__ bool sniff_f32(const unsigned short* xr) {
    int lane = threadIdx.x & 63;
    int bad = 0;
#pragma unroll
    for (int i = 0; i < 16; i++) {
        float v = bf2f(xr[lane * 16 + i]);
        if (!(__builtin_fabsf(v) < 1e10f)) bad = 1;
    }
    return __ballot(bad != 0) != 0ull;
}

// ---------------- fused prep: W transposes (blk<4096), rope tab, x convert ----------------
__global__ __launch_bounds__(256) void prep_k(
    const void* __restrict__ x,
    const void* __restrict__ wq, const void* __restrict__ wk,
    const void* __restrict__ wv, const void* __restrict__ wo,
    unsigned short* __restrict__ WT, unsigned short* __restrict__ WoT,
    float2* __restrict__ tab, unsigned short* __restrict__ xb) {
    int blk = blockIdx.x, t = threadIdx.x;
    bool f32 = sniff_f32((const unsigned short*)x);
    if (blk < 4096) {
        __shared__ unsigned short tile[32][33];
        int mat = blk >> 10, r = blk & 1023;
        const void* src = (mat == 0) ? wq : (mat == 1) ? wk : (mat == 2) ? wv : wo;
        unsigned short* dst = (mat < 3) ? (WT + (size_t)mat * 1048576) : WoT;
        int bx = (r & 31) * 32, by = (r >> 5) * 32;
        int tx = t & 31, ty = t >> 5;  // 32 x 8
#pragma unroll
        for (int j = 0; j < 32; j += 8) {
            size_t idx = (size_t)(by + ty + j) * 1024 + bx + tx;
            float v = f32 ? ((const float*)src)[idx] : bf2f(((const unsigned short*)src)[idx]);
            tile[ty + j][tx] = f2bf(v);
        }
        __syncthreads();
#pragma unroll
        for (int j = 0; j < 32; j += 8)
            dst[(size_t)(bx + ty + j) * 1024 + by + tx] = tile[tx][ty + j];
    } else if (blk < 4352) {
        int i = (blk - 4096) * 256 + t;  // 65536 entries
        int pos = i >> 5, j = i & 31;
        float freq = exp2f(-(float)(2 * j) * (1.0f / 64.0f) * 13.287712379549449f);
        float a = (float)pos * freq;
        tab[i] = make_float2(cosf(a), sinf(a));
    } else {
        size_t base = (size_t)(blk - 4352) * 2048 + (size_t)t * 8;
        if (f32) {
            const float4* s4 = (const float4*)((const float*)x + base);
            float4 a = s4[0], b = s4[1];
            uint4 o;
            o.x = pkbf(a.x, a.y); o.y = pkbf(a.z, a.w);
            o.z = pkbf(b.x, b.y); o.w = pkbf(b.z, b.w);
            *(uint4*)(xb + base) = o;
        } else {
            *(uint4*)(xb + base) = *(const uint4*)((const unsigned short*)x + base);
        }
    }
}

// ---------------- GEMM: C = A * W, Bt = W^T, bf16 MFMA, K=1024, BK=32, tile (128*MT)x128 ----
// MODE 0: O-proj -> d_out (fp32/bf16 per sniff), N=1024
// MODE 1: QKV: N=3072; Q (rope, *0.18034), K (rope), V -> transposed (B,H,d,S)
template <int MODE, int MT>
__global__ __launch_bounds__(256) void gemm_bt(
    const unsigned short* __restrict__ A,
    const unsigned short* __restrict__ Bt,
    void* __restrict__ C0,
    unsigned short* __restrict__ C1,
    unsigned short* __restrict__ C2,
    const float2* __restrict__ tab,
    const unsigned short* __restrict__ xsniff) {
    const int K = 1024;
    __shared__ __align__(16) unsigned short Al[MT * 128 * 32];
    __shared__ __align__(16) unsigned short Bl[128 * 32];

    int m0 = blockIdx.y * (128 * MT);
    int n0 = blockIdx.x * 128;
    int t = threadIdx.x;
    int lane = t & 63, w = t >> 6;
    int quad = lane >> 4, l15 = lane & 15;
    int wm = (w >> 1) * 64, wn = (w & 1) * 64;

    floatx4 acc[MT][4][4];
#pragma unroll
    for (int mt = 0; mt < MT; mt++)
#pragma unroll
        for (int i = 0; i < 4; i++)
#pragma unroll
            for (int j = 0; j < 4; j++) acc[mt][i][j] = (floatx4){0.f, 0.f, 0.f, 0.f};

    for (int k0 = 0; k0 < K; k0 += 32) {
#pragma unroll
        for (int mt = 0; mt < MT; mt++)
#pragma unroll
            for (int c = 0; c < 2; c++) {
                load_lds16(A + (size_t)(m0 + mt * 128 + w * 32 + c * 16 + (lane >> 2)) * K +
                               k0 + (lane & 3) * 8,
                           &Al[(mt * 128 + w * 32 + c * 16) * 32]);
            }
#pragma unroll
        for (int c = 0; c < 2; c++) {
            load_lds16(Bt + (size_t)(n0 + w * 32 + c * 16 + (lane >> 2)) * K + k0 + (lane & 3) * 8,
                       &Bl[(w * 32 + c * 16) * 32]);
        }
        asm volatile("s_waitcnt vmcnt(0)" ::: "memory");
        __syncthreads();

        short8 bfr[4];
#pragma unroll
        for (int j = 0; j < 4; j++)
            bfr[j] = *(const short8*)&Bl[(wn + j * 16 + l15) * 32 + quad * 8];
#pragma unroll
        for (int mt = 0; mt < MT; mt++) {
            short8 af[4];
#pragma unroll
            for (int i = 0; i < 4; i++)
                af[i] = *(const short8*)&Al[(mt * 128 + wm + i * 16 + l15) * 32 + quad * 8];
#pragma unroll
            for (int i = 0; i < 4; i++)
#pragma unroll
                for (int j = 0; j < 4; j++) acc[mt][i][j] = MFMA16(af[i], bfr[j], acc[mt][i][j]);
        }
        __syncthreads();
    }

    bool out_f32 = (MODE == 0) ? sniff_f32(xsniff) : false;
#pragma unroll
    for (int mt = 0; mt < MT; mt++) {
#pragma unroll
        for (int i = 0; i < 4; i++) {
#pragma unroll
            for (int j = 0; j < 4; j++) {
                int col = n0 + wn + j * 16 + l15;
                int row0 = m0 + mt * 128 + wm + i * 16 + quad * 4;
                if (MODE == 0) {
#pragma unroll
                    for (int r = 0; r < 4; r++) {
                        size_t idx = (size_t)(row0 + r) * 1024 + col;
                        if (out_f32) ((float*)C0)[idx] = acc[mt][i][j][r];
                        else ((unsigned short*)C0)[idx] = f2bf(acc[mt][i][j][r]);
                    }
                } else {
                    int which = col >> 10, nn = col & 1023;  // uniform per block
                    int b = row0 >> 11, s0 = row0 & 2047;
                    if (which == 2) {
                        // V^T: (B,H,64,S); 4 consecutive s per fragment column
                        int hh = nn >> 6, d = nn & 63;
                        uint32_t lo = pkbf(acc[mt][i][j][0], acc[mt][i][j][1]);
                        uint32_t hi = pkbf(acc[mt][i][j][2], acc[mt][i][j][3]);
                        *(uint64_t*)(C2 + ((size_t)((b * 16 + hh) * 64 + d)) * 2048 + s0) =
                            (uint64_t)lo | ((uint64_t)hi << 32);
                    } else {
                        int d = nn & 63;
                        unsigned short* dst = (which == 0) ? (unsigned short*)C0 : C1;
                        float sc = (which == 0) ? 0.18033688011112042f : 1.0f;  // 0.125*log2(e)
#pragma unroll
                        for (int r = 0; r < 4; r++) {
                            int s = s0 + r;
                            float v = acc[mt][i][j][r];
                            float pv = __shfl_xor(v, 1);
                            float2 cs = tab[(s << 5) + (d >> 1)];
                            float o = (d & 1) ? (v * cs.x + pv * cs.y) : (v * cs.x - pv * cs.y);
                            dst[((size_t)(b * 2048 + s)) * 1024 + nn] = f2bf(o * sc);
                        }
                    }
                }
            }
        }
    }
}

// ---------------- flash attention v3 (round-8 verified) ----------------
// grid (64, 8): x = b*16+h; y -> q-tile (big-first + pairing). Block 256 = 4 waves.
// Q-tile 256 rows; wave w owns q cols [qt*256+w*64, +64). K-tile 64, processed as 2x mb=32.
// S^T = K·Q^T via 32x32x16 MFMA; P^T assembled in-register; O^T = V^T·P^T.
__global__ __launch_bounds__(256, 2) void flash_k(
    const unsigned short* __restrict__ Qb,
    const unsigned short* __restrict__ Kb,
    const unsigned short* __restrict__ Vt,   // (B,H,64,S)
    unsigned short* __restrict__ A2) {
    __shared__ __align__(16) unsigned short Kl[2][64 * 64];  // [kv][d] swizzled
    __shared__ __align__(16) unsigned short Vl[2][64 * 64];  // [d][kv] swizzled

    int bh = blockIdx.x;
    int y = blockIdx.y;
    int qt = (y < 4) ? (7 - y) : (y - 4);  // big tiles first; y and y+4 pair to 36 iters
    int b = bh >> 4, h = bh & 15;
    int t = threadIdx.x, lane = t & 63, w = t >> 6;
    int l31 = lane & 31, half = lane >> 5;
    size_t base = ((size_t)b * 2048) * 1024 + h * 64;
    int q0w = qt * 256 + w * 64;

    // resident Q^T B-fragments [nb][ks]
    short8 Qf[2][4];
#pragma unroll
    for (int nb = 0; nb < 2; nb++)
#pragma unroll
        for (int ks = 0; ks < 4; ks++)
            Qf[nb][ks] = *(const short8*)(Qb + base + (size_t)(q0w + nb * 32 + l31) * 1024 +
                                          ks * 16 + half * 8);

    floatx16 O[2][2];
#pragma unroll
    for (int i = 0; i < 2; i++)
#pragma unroll
        for (int j = 0; j < 2; j++) O[i][j] = (floatx16)0.0f;
    float lsum[2] = {0.f, 0.f};

    int nk = 4 * (qt + 1);

    int srow = t >> 2;
    const unsigned short* kg = Kb + base + (size_t)srow * 1024 + (t & 3) * 16;
    const unsigned short* vg = Vt + ((size_t)(bh * 64 + srow)) * 2048 + (t & 3) * 16;
    int sw0 = srow * 64 + ((((t & 3) * 2 + 0) ^ (srow & 7)) * 8);
    int sw1 = srow * 64 + ((((t & 3) * 2 + 1) ^ (srow & 7)) * 8);

    short8 rk0 = *(const short8*)(kg);
    short8 rk1 = *(const short8*)(kg + 8);
    short8 rv0 = *(const short8*)(vg);
    short8 rv1 = *(const short8*)(vg + 8);

    for (int kt = 0; kt < nk; kt++) {
        int k0 = kt * 64, bf = kt & 1;
        *(short8*)&Kl[bf][sw0] = rk0;
        *(short8*)&Kl[bf][sw1] = rk1;
        *(short8*)&Vl[bf][sw0] = rv0;
        *(short8*)&Vl[bf][sw1] = rv1;
        __syncthreads();
        if (kt + 1 < nk) {
            size_t ko = (size_t)(kt + 1) * 64;
            rk0 = *(const short8*)(kg + ko * 1024);
            rk1 = *(const short8*)(kg + ko * 1024 + 8);
            rv0 = *(const short8*)(vg + ko);
            rv1 = *(const short8*)(vg + ko + 8);
        }
#pragma unroll
        for (int mb = 0; mb < 2; mb++) {
            if (k0 + mb * 32 >= q0w + 64) continue;  // fully-masked 32-row band
            short8 Ka[4];
#pragma unroll
            for (int ks = 0; ks < 4; ks++)
                Ka[ks] = *(const short8*)&Kl[bf][(mb * 32 + l31) * 64 +
                                                 (((ks * 2 + half) ^ (l31 & 7)) * 8)];
            floatx16 Sc[2];
#pragma unroll
            for (int nb = 0; nb < 2; nb++) Sc[nb] = (floatx16)0.0f;
#pragma unroll
            for (int nb = 0; nb < 2; nb++)
#pragma unroll
                for (int ks = 0; ks < 4; ks++)
                    Sc[nb] = MFMA32(Ka[ks], Qf[nb][ks], Sc[nb]);

            bool domask = (k0 + mb * 32 + 31 > q0w);
            uint32_t pkm[2][8];  // [nb][pair]
#pragma unroll
            for (int nb = 0; nb < 2; nb++) {
                float p[16];
#pragma unroll
                for (int e = 0; e < 16; e++) {
                    float v = exp2f(Sc[nb][e]);
                    if (domask) {
                        int kv = k0 + mb * 32 + (e & 3) + ((e >> 2) << 3) + half * 4;
                        int qq = q0w + nb * 32 + l31;
                        v = (kv > qq) ? 0.f : v;
                    }
                    p[e] = v;
                }
                float t0 = (p[0] + p[1]) + (p[2] + p[3]);
                float t1 = (p[4] + p[5]) + (p[6] + p[7]);
                float t2 = (p[8] + p[9]) + (p[10] + p[11]);
                float t3 = (p[12] + p[13]) + (p[14] + p[15]);
                lsum[nb] += (t0 + t1) + (t2 + t3);
#pragma unroll
                for (int jj = 0; jj < 8; jj++)
                    pkm[nb][jj] = pkbf(p[2 * jj], p[2 * jj + 1]);
            }

            short8 Va[2][2];  // [db][ks2]
#pragma unroll
            for (int db = 0; db < 2; db++)
#pragma unroll
                for (int ks2 = 0; ks2 < 2; ks2++)
                    Va[db][ks2] = *(const short8*)&Vl[bf][(db * 32 + l31) * 64 +
                                                         ((((mb * 2 + ks2) * 2 + half) ^ (l31 & 7)) * 8)];
#pragma unroll
            for (int ks2 = 0; ks2 < 2; ks2++) {
#pragma unroll
                for (int nb = 0; nb < 2; nb++) {
                    uint32_t p0 = pkm[nb][4 * ks2 + 0];
                    uint32_t p1 = pkm[nb][4 * ks2 + 1];
                    uint32_t p2 = pkm[nb][4 * ks2 + 2];
                    uint32_t p3 = pkm[nb][4 * ks2 + 3];
                    uint32_t u = half ? p0 : p2;
                    uint32_t v2 = half ? p1 : p3;
                    uint32_t ya = (uint32_t)__shfl_xor((int)u, 32);
                    uint32_t yb = (uint32_t)__shfl_xor((int)v2, 32);
                    union { short8 s; uint32_t q[4]; } bb;
                    bb.q[0] = half ? ya : p0;
                    bb.q[1] = half ? yb : p1;
                    bb.q[2] = half ? p2 : ya;
                    bb.q[3] = half ? p3 : yb;
#pragma unroll
                    for (int db = 0; db < 2; db++)
                        O[db][nb] = MFMA32(Va[db][ks2], bb.s, O[db][nb]);
                }
            }
        }
    }

    float inv[2];
#pragma unroll
    for (int nb = 0; nb < 2; nb++) {
        float tot = lsum[nb] + __shfl_xor(lsum[nb], 32);
        inv[nb] = 1.0f / tot;
    }
#pragma unroll
    for (int db = 0; db < 2; db++) {
#pragma unroll
        for (int nb = 0; nb < 2; nb++) {
            int scol = q0w + nb * 32 + l31;
            unsigned short* op = A2 + base + (size_t)scol * 1024;
#pragma unroll
            for (int g = 0; g < 4; g++) {
                int d0 = db * 32 + half * 4 + g * 8;
                float v0 = O[db][nb][g * 4 + 0] * inv[nb];
                float v1 = O[db][nb][g * 4 + 1] * inv[nb];
                float v2 = O[db][nb][g * 4 + 2] * inv[nb];
                float v3 = O[db][nb][g * 4 + 3] * inv[nb];
                uint32_t lo = pkbf(v0, v1), hi = pkbf(v2, v3);
                *(uint64_t*)(op + d0) = (uint64_t)lo | ((uint64_t)hi << 32);
            }
        }
    }
}

extern "C" void kernel_launch(void* const* d_in, const int* in_sizes, int n_in,
                              void* d_out, int out_size, void* d_ws, size_t ws_size,
                              hipStream_t stream) {
    const void* x  = d_in[0];
    const void* wq = d_in[1];
    const void* wk = d_in[2];
    const void* wv = d_in[3];
    const void* wo = d_in[4];

    char* ws = (char*)d_ws;
    unsigned short* WT  = (unsigned short*)(ws);                        // 3x1024x1024 bf16
    unsigned short* WoT = (unsigned short*)(ws + 6291456);              // 1024x1024 bf16
    float2*         tab = (float2*)(ws + 8388608);                      // 2048x32 float2
    unsigned short* xb  = (unsigned short*)(ws + 8913920);              // 16 MB bf16 x
    unsigned short* Qb  = (unsigned short*)(ws + 8913920 + 16777216ull);
    unsigned short* Kb  = (unsigned short*)(ws + 8913920 + 2ull * 16777216);
    unsigned short* Vt  = (unsigned short*)(ws + 8913920 + 3ull * 16777216);  // (B,H,64,S)
    unsigned short* A2  = xb;  // alias: xb dead after QKV GEMM

    prep_k<<<8448, 256, 0, stream>>>(x, wq, wk, wv, wo, WT, WoT, tab, xb);

    gemm_bt<1, 2><<<dim3(24, 32), 256, 0, stream>>>(xb, WT, Qb, Kb, Vt, tab,
                                                    (const unsigned short*)x);
    flash_k<<<dim3(64, 8), 256, 0, stream>>>(Qb, Kb, Vt, A2);
    gemm_bt<0, 1><<<dim3(8, 64), 256, 0, stream>>>(A2, WoT, d_out, nullptr, nullptr, tab,
                                                   (const unsigned short*)x);
}

// Round 10
// 293.662 us; speedup vs baseline: 1.1843x; 1.1843x over previous
//
#include <hip/hip_runtime.h>
#include <hip/hip_bf16.h>
#include <stdint.h>

// MHA forward, fp32/bf16 in/out auto-detected, bf16 MFMA internal. MI355X gfx950.
// prep (W transpose, rope tab, x cvt; per-block dtype sniff) -> QKV GEMM (128x128, BK=32,
// double-buffered LDS, +RoPE, Q pre-scaled, V transposed (B,H,d,S)) -> flash attn ->
// O-proj GEMM (same dbuf structure).
// Tile-size experiments BK=64 (r7) and MT=2 (r9) both hit the 128-VGPR occupancy cliff;
// dbuf grows LDS only (32KB: still 4 blocks/CU) and keeps VGPR <= 128.

typedef __attribute__((ext_vector_type(8))) short short8;
typedef __attribute__((ext_vector_type(4))) float floatx4;
typedef __attribute__((ext_vector_type(16))) float floatx16;

#define MFMA16(a,b,c) __builtin_amdgcn_mfma_f32_16x16x32_bf16((a),(b),(c),0,0,0)
#define MFMA32(a,b,c) __builtin_amdgcn_mfma_f32_32x32x16_bf16((a),(b),(c),0,0,0)

__device__ __forceinline__ uint32_t fbits(float f){ uint32_t u; __builtin_memcpy(&u,&f,4); return u; }
__device__ __forceinline__ unsigned short f2bf(float f) {
    uint32_t u = fbits(f);
    return (unsigned short)((u + 0x7fffu + ((u>>16)&1u)) >> 16);
}
__device__ __forceinline__ float bf2f(unsigned short s){ uint32_t u = (uint32_t)s<<16; float f; __builtin_memcpy(&f,&u,4); return f; }
// pack two floats to bf16 pair (round-half-up), lo in low 16
__device__ __forceinline__ uint32_t pkbf(float lo, float hi) {
    return __builtin_amdgcn_perm(fbits(hi)+0x8000u, fbits(lo)+0x8000u, 0x07060302u);
}

__device__ __forceinline__ void load_lds16(const unsigned short* g, unsigned short* l) {
    __builtin_amdgcn_global_load_lds(
        (const __attribute__((address_space(1))) void*)g,
        (__attribute__((address_space(3))) void*)l, 16, 0, 0);
}

// wave-local dtype sniff: reinterpret first 1024 shorts of x as bf16; fp32 source shows
// huge/NaN patterns in mantissa halves with overwhelming probability.
__device__ __forceinline__ bool sniff_f32(const unsigned short* xr) {
    int lane = threadIdx.x & 63;
    int bad = 0;
#pragma unroll
    for (int i = 0; i < 16; i++) {
        float v = bf2f(xr[lane * 16 + i]);
        if (!(__builtin_fabsf(v) < 1e10f)) bad = 1;
    }
    return __ballot(bad != 0) != 0ull;
}

// ---------------- fused prep: W transposes (blk<4096), rope tab, x convert ----------------
__global__ __launch_bounds__(256) void prep_k(
    const void* __restrict__ x,
    const void* __restrict__ wq, const void* __restrict__ wk,
    const void* __restrict__ wv, const void* __restrict__ wo,
    unsigned short* __restrict__ WT, unsigned short* __restrict__ WoT,
    float2* __restrict__ tab, unsigned short* __restrict__ xb) {
    int blk = blockIdx.x, t = threadIdx.x;
    bool f32 = sniff_f32((const unsigned short*)x);
    if (blk < 4096) {
        __shared__ unsigned short tile[32][33];
        int mat = blk >> 10, r = blk & 1023;
        const void* src = (mat == 0) ? wq : (mat == 1) ? wk : (mat == 2) ? wv : wo;
        unsigned short* dst = (mat < 3) ? (WT + (size_t)mat * 1048576) : WoT;
        int bx = (r & 31) * 32, by = (r >> 5) * 32;
        int tx = t & 31, ty = t >> 5;  // 32 x 8
#pragma unroll
        for (int j = 0; j < 32; j += 8) {
            size_t idx = (size_t)(by + ty + j) * 1024 + bx + tx;
            float v = f32 ? ((const float*)src)[idx] : bf2f(((const unsigned short*)src)[idx]);
            tile[ty + j][tx] = f2bf(v);
        }
        __syncthreads();
#pragma unroll
        for (int j = 0; j < 32; j += 8)
            dst[(size_t)(bx + ty + j) * 1024 + by + tx] = tile[tx][ty + j];
    } else if (blk < 4352) {
        int i = (blk - 4096) * 256 + t;  // 65536 entries
        int pos = i >> 5, j = i & 31;
        float freq = exp2f(-(float)(2 * j) * (1.0f / 64.0f) * 13.287712379549449f);
        float a = (float)pos * freq;
        tab[i] = make_float2(cosf(a), sinf(a));
    } else {
        size_t base = (size_t)(blk - 4352) * 2048 + (size_t)t * 8;
        if (f32) {
            const float4* s4 = (const float4*)((const float*)x + base);
            float4 a = s4[0], b = s4[1];
            uint4 o;
            o.x = pkbf(a.x, a.y); o.y = pkbf(a.z, a.w);
            o.z = pkbf(b.x, b.y); o.w = pkbf(b.z, b.w);
            *(uint4*)(xb + base) = o;
        } else {
            *(uint4*)(xb + base) = *(const uint4*)((const unsigned short*)x + base);
        }
    }
}

// ---------------- GEMM: C = A * W, Bt = W^T, bf16 MFMA, K=1024, BK=32, 128x128, LDS dbuf ----
// MODE 0: O-proj -> d_out (fp32/bf16 per sniff), N=1024
// MODE 1: QKV: N=3072; Q (rope, *0.18034), K (rope), V -> transposed (B,H,d,S)
template <int MODE>
__global__ __launch_bounds__(256) void gemm_bt(
    const unsigned short* __restrict__ A,
    const unsigned short* __restrict__ Bt,
    void* __restrict__ C0,
    unsigned short* __restrict__ C1,
    unsigned short* __restrict__ C2,
    const float2* __restrict__ tab,
    const unsigned short* __restrict__ xsniff) {
    const int K = 1024;
    __shared__ __align__(16) unsigned short Al[2][128 * 32];
    __shared__ __align__(16) unsigned short Bl[2][128 * 32];

    int m0 = blockIdx.y * 128;
    int n0 = blockIdx.x * 128;
    int t = threadIdx.x;
    int lane = t & 63, w = t >> 6;
    int quad = lane >> 4, l15 = lane & 15;
    int wm = (w >> 1) * 64, wn = (w & 1) * 64;

    floatx4 acc[4][4];
#pragma unroll
    for (int i = 0; i < 4; i++)
#pragma unroll
        for (int j = 0; j < 4; j++) acc[i][j] = (floatx4){0.f, 0.f, 0.f, 0.f};

    // staging: wave w covers rows w*32+c*16+(lane>>2), 16B chunk (lane&3)*8 shorts
    const unsigned short* ag[2];
    const unsigned short* bg[2];
    int lofs[2];
#pragma unroll
    for (int c = 0; c < 2; c++) {
        int row = w * 32 + c * 16 + (lane >> 2);
        ag[c] = A + (size_t)(m0 + row) * K + (lane & 3) * 8;
        bg[c] = Bt + (size_t)(n0 + row) * K + (lane & 3) * 8;
        lofs[c] = (w * 32 + c * 16) * 32;
    }

    // preload tile 0 -> buf 0
#pragma unroll
    for (int c = 0; c < 2; c++) {
        load_lds16(ag[c], &Al[0][lofs[c]]);
        load_lds16(bg[c], &Bl[0][lofs[c]]);
        ag[c] += 32; bg[c] += 32;
    }
    asm volatile("s_waitcnt vmcnt(0)" ::: "memory");
    __syncthreads();

    for (int kk = 0; kk < 16; kk++) {
        // even tile (2kk) in buf0: prefetch 2kk+1 -> buf1, compute buf0
#pragma unroll
        for (int c = 0; c < 2; c++) {
            load_lds16(ag[c], &Al[1][lofs[c]]);
            load_lds16(bg[c], &Bl[1][lofs[c]]);
            ag[c] += 32; bg[c] += 32;
        }
        {
            short8 af[4], bfr[4];
#pragma unroll
            for (int i = 0; i < 4; i++)
                af[i] = *(const short8*)&Al[0][(wm + i * 16 + l15) * 32 + quad * 8];
#pragma unroll
            for (int j = 0; j < 4; j++)
                bfr[j] = *(const short8*)&Bl[0][(wn + j * 16 + l15) * 32 + quad * 8];
#pragma unroll
            for (int i = 0; i < 4; i++)
#pragma unroll
                for (int j = 0; j < 4; j++) acc[i][j] = MFMA16(af[i], bfr[j], acc[i][j]);
        }
        asm volatile("s_waitcnt vmcnt(0)" ::: "memory");
        __syncthreads();

        // odd tile (2kk+1) in buf1: prefetch 2kk+2 -> buf0 (unless last), compute buf1
        if (kk < 15) {
#pragma unroll
            for (int c = 0; c < 2; c++) {
                load_lds16(ag[c], &Al[0][lofs[c]]);
                load_lds16(bg[c], &Bl[0][lofs[c]]);
                ag[c] += 32; bg[c] += 32;
            }
        }
        {
            short8 af[4], bfr[4];
#pragma unroll
            for (int i = 0; i < 4; i++)
                af[i] = *(const short8*)&Al[1][(wm + i * 16 + l15) * 32 + quad * 8];
#pragma unroll
            for (int j = 0; j < 4; j++)
                bfr[j] = *(const short8*)&Bl[1][(wn + j * 16 + l15) * 32 + quad * 8];
#pragma unroll
            for (int i = 0; i < 4; i++)
#pragma unroll
                for (int j = 0; j < 4; j++) acc[i][j] = MFMA16(af[i], bfr[j], acc[i][j]);
        }
        asm volatile("s_waitcnt vmcnt(0)" ::: "memory");
        __syncthreads();
    }

    bool out_f32 = (MODE == 0) ? sniff_f32(xsniff) : false;
#pragma unroll
    for (int i = 0; i < 4; i++) {
#pragma unroll
        for (int j = 0; j < 4; j++) {
            int col = n0 + wn + j * 16 + l15;
            int row0 = m0 + wm + i * 16 + quad * 4;
            if (MODE == 0) {
#pragma unroll
                for (int r = 0; r < 4; r++) {
                    size_t idx = (size_t)(row0 + r) * 1024 + col;
                    if (out_f32) ((float*)C0)[idx] = acc[i][j][r];
                    else ((unsigned short*)C0)[idx] = f2bf(acc[i][j][r]);
                }
            } else {
                int which = col >> 10, nn = col & 1023;  // uniform per block
                int b = row0 >> 11, s0 = row0 & 2047;
                if (which == 2) {
                    // V^T: (B,H,64,S); 4 consecutive s per fragment column
                    int hh = nn >> 6, d = nn & 63;
                    uint32_t lo = pkbf(acc[i][j][0], acc[i][j][1]);
                    uint32_t hi = pkbf(acc[i][j][2], acc[i][j][3]);
                    *(uint64_t*)(C2 + ((size_t)((b * 16 + hh) * 64 + d)) * 2048 + s0) =
                        (uint64_t)lo | ((uint64_t)hi << 32);
                } else {
                    int d = nn & 63;
                    unsigned short* dst = (which == 0) ? (unsigned short*)C0 : C1;
                    float sc = (which == 0) ? 0.18033688011112042f : 1.0f;  // 0.125*log2(e)
#pragma unroll
                    for (int r = 0; r < 4; r++) {
                        int s = s0 + r;
                        float v = acc[i][j][r];
                        float pv = __shfl_xor(v, 1);
                        float2 cs = tab[(s << 5) + (d >> 1)];
                        float o = (d & 1) ? (v * cs.x + pv * cs.y) : (v * cs.x - pv * cs.y);
                        dst[((size_t)(b * 2048 + s)) * 1024 + nn] = f2bf(o * sc);
                    }
                }
            }
        }
    }
}

// ---------------- flash attention v3 (round-8 verified) ----------------
// grid (64, 8): x = b*16+h; y -> q-tile (big-first + pairing). Block 256 = 4 waves.
// Q-tile 256 rows; wave w owns q cols [qt*256+w*64, +64). K-tile 64, processed as 2x mb=32.
// S^T = K·Q^T via 32x32x16 MFMA; P^T assembled in-register; O^T = V^T·P^T.
__global__ __launch_bounds__(256, 2) void flash_k(
    const unsigned short* __restrict__ Qb,
    const unsigned short* __restrict__ Kb,
    const unsigned short* __restrict__ Vt,   // (B,H,64,S)
    unsigned short* __restrict__ A2) {
    __shared__ __align__(16) unsigned short Kl[2][64 * 64];  // [kv][d] swizzled
    __shared__ __align__(16) unsigned short Vl[2][64 * 64];  // [d][kv] swizzled

    int bh = blockIdx.x;
    int y = blockIdx.y;
    int qt = (y < 4) ? (7 - y) : (y - 4);  // big tiles first; y and y+4 pair to 36 iters
    int b = bh >> 4, h = bh & 15;
    int t = threadIdx.x, lane = t & 63, w = t >> 6;
    int l31 = lane & 31, half = lane >> 5;
    size_t base = ((size_t)b * 2048) * 1024 + h * 64;
    int q0w = qt * 256 + w * 64;

    // resident Q^T B-fragments [nb][ks]
    short8 Qf[2][4];
#pragma unroll
    for (int nb = 0; nb < 2; nb++)
#pragma unroll
        for (int ks = 0; ks < 4; ks++)
            Qf[nb][ks] = *(const short8*)(Qb + base + (size_t)(q0w + nb * 32 + l31) * 1024 +
                                          ks * 16 + half * 8);

    floatx16 O[2][2];
#pragma unroll
    for (int i = 0; i < 2; i++)
#pragma unroll
        for (int j = 0; j < 2; j++) O[i][j] = (floatx16)0.0f;
    float lsum[2] = {0.f, 0.f};

    int nk = 4 * (qt + 1);

    int srow = t >> 2;
    const unsigned short* kg = Kb + base + (size_t)srow * 1024 + (t & 3) * 16;
    const unsigned short* vg = Vt + ((size_t)(bh * 64 + srow)) * 2048 + (t & 3) * 16;
    int sw0 = srow * 64 + ((((t & 3) * 2 + 0) ^ (srow & 7)) * 8);
    int sw1 = srow * 64 + ((((t & 3) * 2 + 1) ^ (srow & 7)) * 8);

    short8 rk0 = *(const short8*)(kg);
    short8 rk1 = *(const short8*)(kg + 8);
    short8 rv0 = *(const short8*)(vg);
    short8 rv1 = *(const short8*)(vg + 8);

    for (int kt = 0; kt < nk; kt++) {
        int k0 = kt * 64, bf = kt & 1;
        *(short8*)&Kl[bf][sw0] = rk0;
        *(short8*)&Kl[bf][sw1] = rk1;
        *(short8*)&Vl[bf][sw0] = rv0;
        *(short8*)&Vl[bf][sw1] = rv1;
        __syncthreads();
        if (kt + 1 < nk) {
            size_t ko = (size_t)(kt + 1) * 64;
            rk0 = *(const short8*)(kg + ko * 1024);
            rk1 = *(const short8*)(kg + ko * 1024 + 8);
            rv0 = *(const short8*)(vg + ko);
            rv1 = *(const short8*)(vg + ko + 8);
        }
#pragma unroll
        for (int mb = 0; mb < 2; mb++) {
            if (k0 + mb * 32 >= q0w + 64) continue;  // fully-masked 32-row band
            short8 Ka[4];
#pragma unroll
            for (int ks = 0; ks < 4; ks++)
                Ka[ks] = *(const short8*)&Kl[bf][(mb * 32 + l31) * 64 +
                                                 (((ks * 2 + half) ^ (l31 & 7)) * 8)];
            floatx16 Sc[2];
#pragma unroll
            for (int nb = 0; nb < 2; nb++) Sc[nb] = (floatx16)0.0f;
#pragma unroll
            for (int nb = 0; nb < 2; nb++)
#pragma unroll
                for (int ks = 0; ks < 4; ks++)
                    Sc[nb] = MFMA32(Ka[ks], Qf[nb][ks], Sc[nb]);

            bool domask = (k0 + mb * 32 + 31 > q0w);
            uint32_t pkm[2][8];  // [nb][pair]
#pragma unroll
            for (int nb = 0; nb < 2; nb++) {
                float p[16];
#pragma unroll
                for (int e = 0; e < 16; e++) {
                    float v = exp2f(Sc[nb][e]);
                    if (domask) {
                        int kv = k0 + mb * 32 + (e & 3) + ((e >> 2) << 3) + half * 4;
                        int qq = q0w + nb * 32 + l31;
                        v = (kv > qq) ? 0.f : v;
                    }
                    p[e] = v;
                }
                float t0 = (p[0] + p[1]) + (p[2] + p[3]);
                float t1 = (p[4] + p[5]) + (p[6] + p[7]);
                float t2 = (p[8] + p[9]) + (p[10] + p[11]);
                float t3 = (p[12] + p[13]) + (p[14] + p[15]);
                lsum[nb] += (t0 + t1) + (t2 + t3);
#pragma unroll
                for (int jj = 0; jj < 8; jj++)
                    pkm[nb][jj] = pkbf(p[2 * jj], p[2 * jj + 1]);
            }

            short8 Va[2][2];  // [db][ks2]
#pragma unroll
            for (int db = 0; db < 2; db++)
#pragma unroll
                for (int ks2 = 0; ks2 < 2; ks2++)
                    Va[db][ks2] = *(const short8*)&Vl[bf][(db * 32 + l31) * 64 +
                                                         ((((mb * 2 + ks2) * 2 + half) ^ (l31 & 7)) * 8)];
#pragma unroll
            for (int ks2 = 0; ks2 < 2; ks2++) {
#pragma unroll
                for (int nb = 0; nb < 2; nb++) {
                    uint32_t p0 = pkm[nb][4 * ks2 + 0];
                    uint32_t p1 = pkm[nb][4 * ks2 + 1];
                    uint32_t p2 = pkm[nb][4 * ks2 + 2];
                    uint32_t p3 = pkm[nb][4 * ks2 + 3];
                    uint32_t u = half ? p0 : p2;
                    uint32_t v2 = half ? p1 : p3;
                    uint32_t ya = (uint32_t)__shfl_xor((int)u, 32);
                    uint32_t yb = (uint32_t)__shfl_xor((int)v2, 32);
                    union { short8 s; uint32_t q[4]; } bb;
                    bb.q[0] = half ? ya : p0;
                    bb.q[1] = half ? yb : p1;
                    bb.q[2] = half ? p2 : ya;
                    bb.q[3] = half ? p3 : yb;
#pragma unroll
                    for (int db = 0; db < 2; db++)
                        O[db][nb] = MFMA32(Va[db][ks2], bb.s, O[db][nb]);
                }
            }
        }
    }

    float inv[2];
#pragma unroll
    for (int nb = 0; nb < 2; nb++) {
        float tot = lsum[nb] + __shfl_xor(lsum[nb], 32);
        inv[nb] = 1.0f / tot;
    }
#pragma unroll
    for (int db = 0; db < 2; db++) {
#pragma unroll
        for (int nb = 0; nb < 2; nb++) {
            int scol = q0w + nb * 32 + l31;
            unsigned short* op = A2 + base + (size_t)scol * 1024;
#pragma unroll
            for (int g = 0; g < 4; g++) {
                int d0 = db * 32 + half * 4 + g * 8;
                float v0 = O[db][nb][g * 4 + 0] * inv[nb];
                float v1 = O[db][nb][g * 4 + 1] * inv[nb];
                float v2 = O[db][nb][g * 4 + 2] * inv[nb];
                float v3 = O[db][nb][g * 4 + 3] * inv[nb];
                uint32_t lo = pkbf(v0, v1), hi = pkbf(v2, v3);
                *(uint64_t*)(op + d0) = (uint64_t)lo | ((uint64_t)hi << 32);
            }
        }
    }
}

extern "C" void kernel_launch(void* const* d_in, const int* in_sizes, int n_in,
                              void* d_out, int out_size, void* d_ws, size_t ws_size,
                              hipStream_t stream) {
    const void* x  = d_in[0];
    const void* wq = d_in[1];
    const void* wk = d_in[2];
    const void* wv = d_in[3];
    const void* wo = d_in[4];

    char* ws = (char*)d_ws;
    unsigned short* WT  = (unsigned short*)(ws);                        // 3x1024x1024 bf16
    unsigned short* WoT = (unsigned short*)(ws + 6291456);              // 1024x1024 bf16
    float2*         tab = (float2*)(ws + 8388608);                      // 2048x32 float2
    unsigned short* xb  = (unsigned short*)(ws + 8913920);              // 16 MB bf16 x
    unsigned short* Qb  = (unsigned short*)(ws + 8913920 + 16777216ull);
    unsigned short* Kb  = (unsigned short*)(ws + 8913920 + 2ull * 16777216);
    unsigned short* Vt  = (unsigned short*)(ws + 8913920 + 3ull * 16777216);  // (B,H,64,S)
    unsigned short* A2  = xb;  // alias: xb dead after QKV GEMM

    prep_k<<<8448, 256, 0, stream>>>(x, wq, wk, wv, wo, WT, WoT, tab, xb);

    gemm_bt<1><<<dim3(24, 64), 256, 0, stream>>>(xb, WT, Qb, Kb, Vt, tab,
                                                 (const unsigned short*)x);
    flash_k<<<dim3(64, 8), 256, 0, stream>>>(Qb, Kb, Vt, A2);
    gemm_bt<0><<<dim3(8, 64), 256, 0, stream>>>(A2, WoT, d_out, nullptr, nullptr, tab,
                                                (const unsigned short*)x);
}

// Round 11
// 272.300 us; speedup vs baseline: 1.2772x; 1.0784x over previous
//
#include <hip/hip_runtime.h>
#include <hip/hip_bf16.h>
#include <stdint.h>

// MHA forward, fp32/bf16 in/out auto-detected, bf16 MFMA internal. MI355X gfx950.
// prep (W transpose, rope tab, x cvt) -> QKV GEMM (128x128, BK=32, LDS dbuf, +RoPE,
// V transposed (B,H,d,S)) -> flash attn (q-tile 128, 4 blocks/CU, S^T orientation) ->
// O-proj GEMM (dbuf). History: BK=64 (r7) / MT=2 (r9) hit the 128-VGPR occupancy cliff;
// dbuf (r10) verified win; flash q-tile halved (r11) to fill 4 blocks/CU.

typedef __attribute__((ext_vector_type(8))) short short8;
typedef __attribute__((ext_vector_type(4))) float floatx4;
typedef __attribute__((ext_vector_type(16))) float floatx16;

#define MFMA16(a,b,c) __builtin_amdgcn_mfma_f32_16x16x32_bf16((a),(b),(c),0,0,0)
#define MFMA32(a,b,c) __builtin_amdgcn_mfma_f32_32x32x16_bf16((a),(b),(c),0,0,0)

__device__ __forceinline__ uint32_t fbits(float f){ uint32_t u; __builtin_memcpy(&u,&f,4); return u; }
__device__ __forceinline__ unsigned short f2bf(float f) {
    uint32_t u = fbits(f);
    return (unsigned short)((u + 0x7fffu + ((u>>16)&1u)) >> 16);
}
__device__ __forceinline__ float bf2f(unsigned short s){ uint32_t u = (uint32_t)s<<16; float f; __builtin_memcpy(&f,&u,4); return f; }
// pack two floats to bf16 pair, lo in low 16. Single v_cvt_pk_bf16_f32 when available.
__device__ __forceinline__ uint32_t pkbf(float lo, float hi) {
#if __has_builtin(__builtin_amdgcn_cvt_pk_bf16_f32)
    auto r = __builtin_amdgcn_cvt_pk_bf16_f32(lo, hi);
    uint32_t u; __builtin_memcpy(&u, &r, sizeof(u));
    return u;
#else
    return __builtin_amdgcn_perm(fbits(hi)+0x8000u, fbits(lo)+0x8000u, 0x07060302u);
#endif
}

__device__ __forceinline__ void load_lds16(const unsigned short* g, unsigned short* l) {
    __builtin_amdgcn_global_load_lds(
        (const __attribute__((address_space(1))) void*)g,
        (__attribute__((address_space(3))) void*)l, 16, 0, 0);
}

// wave-local dtype sniff: reinterpret first 1024 shorts of x as bf16; fp32 source shows
// huge/NaN patterns in mantissa halves with overwhelming probability.
__device__ __forceinline__ bool sniff_f32(const unsigned short* xr) {
    int lane = threadIdx.x & 63;
    int bad = 0;
#pragma unroll
    for (int i = 0; i < 16; i++) {
        float v = bf2f(xr[lane * 16 + i]);
        if (!(__builtin_fabsf(v) < 1e10f)) bad = 1;
    }
    return __ballot(bad != 0) != 0ull;
}

// ---------------- fused prep: W transposes (blk<4096), rope tab, x convert ----------------
__global__ __launch_bounds__(256) void prep_k(
    const void* __restrict__ x,
    const void* __restrict__ wq, const void* __restrict__ wk,
    const void* __restrict__ wv, const void* __restrict__ wo,
    unsigned short* __restrict__ WT, unsigned short* __restrict__ WoT,
    float2* __restrict__ tab, unsigned short* __restrict__ xb) {
    int blk = blockIdx.x, t = threadIdx.x;
    bool f32 = sniff_f32((const unsigned short*)x);
    if (blk < 4096) {
        __shared__ unsigned short tile[32][33];
        int mat = blk >> 10, r = blk & 1023;
        const void* src = (mat == 0) ? wq : (mat == 1) ? wk : (mat == 2) ? wv : wo;
        unsigned short* dst = (mat < 3) ? (WT + (size_t)mat * 1048576) : WoT;
        int bx = (r & 31) * 32, by = (r >> 5) * 32;
        int tx = t & 31, ty = t >> 5;  // 32 x 8
#pragma unroll
        for (int j = 0; j < 32; j += 8) {
            size_t idx = (size_t)(by + ty + j) * 1024 + bx + tx;
            float v = f32 ? ((const float*)src)[idx] : bf2f(((const unsigned short*)src)[idx]);
            tile[ty + j][tx] = f2bf(v);
        }
        __syncthreads();
#pragma unroll
        for (int j = 0; j < 32; j += 8)
            dst[(size_t)(bx + ty + j) * 1024 + by + tx] = tile[tx][ty + j];
    } else if (blk < 4352) {
        int i = (blk - 4096) * 256 + t;  // 65536 entries
        int pos = i >> 5, j = i & 31;
        float freq = exp2f(-(float)(2 * j) * (1.0f / 64.0f) * 13.287712379549449f);
        float a = (float)pos * freq;
        tab[i] = make_float2(cosf(a), sinf(a));
    } else {
        size_t base = (size_t)(blk - 4352) * 2048 + (size_t)t * 8;
        if (f32) {
            const float4* s4 = (const float4*)((const float*)x + base);
            float4 a = s4[0], b = s4[1];
            uint4 o;
            o.x = pkbf(a.x, a.y); o.y = pkbf(a.z, a.w);
            o.z = pkbf(b.x, b.y); o.w = pkbf(b.z, b.w);
            *(uint4*)(xb + base) = o;
        } else {
            *(uint4*)(xb + base) = *(const uint4*)((const unsigned short*)x + base);
        }
    }
}

// ---------------- GEMM: C = A * W, Bt = W^T, bf16 MFMA, K=1024, BK=32, 128x128, LDS dbuf ----
// MODE 0: O-proj -> d_out (fp32/bf16 per sniff), N=1024
// MODE 1: QKV: N=3072; Q (rope, *0.18034), K (rope), V -> transposed (B,H,d,S)
template <int MODE>
__global__ __launch_bounds__(256) void gemm_bt(
    const unsigned short* __restrict__ A,
    const unsigned short* __restrict__ Bt,
    void* __restrict__ C0,
    unsigned short* __restrict__ C1,
    unsigned short* __restrict__ C2,
    const float2* __restrict__ tab,
    const unsigned short* __restrict__ xsniff) {
    const int K = 1024;
    __shared__ __align__(16) unsigned short Al[2][128 * 32];
    __shared__ __align__(16) unsigned short Bl[2][128 * 32];

    int m0 = blockIdx.y * 128;
    int n0 = blockIdx.x * 128;
    int t = threadIdx.x;
    int lane = t & 63, w = t >> 6;
    int quad = lane >> 4, l15 = lane & 15;
    int wm = (w >> 1) * 64, wn = (w & 1) * 64;

    floatx4 acc[4][4];
#pragma unroll
    for (int i = 0; i < 4; i++)
#pragma unroll
        for (int j = 0; j < 4; j++) acc[i][j] = (floatx4){0.f, 0.f, 0.f, 0.f};

    const unsigned short* ag[2];
    const unsigned short* bg[2];
    int lofs[2];
#pragma unroll
    for (int c = 0; c < 2; c++) {
        int row = w * 32 + c * 16 + (lane >> 2);
        ag[c] = A + (size_t)(m0 + row) * K + (lane & 3) * 8;
        bg[c] = Bt + (size_t)(n0 + row) * K + (lane & 3) * 8;
        lofs[c] = (w * 32 + c * 16) * 32;
    }

    // preload tile 0 -> buf 0
#pragma unroll
    for (int c = 0; c < 2; c++) {
        load_lds16(ag[c], &Al[0][lofs[c]]);
        load_lds16(bg[c], &Bl[0][lofs[c]]);
        ag[c] += 32; bg[c] += 32;
    }
    asm volatile("s_waitcnt vmcnt(0)" ::: "memory");
    __syncthreads();

    for (int kk = 0; kk < 16; kk++) {
#pragma unroll
        for (int c = 0; c < 2; c++) {
            load_lds16(ag[c], &Al[1][lofs[c]]);
            load_lds16(bg[c], &Bl[1][lofs[c]]);
            ag[c] += 32; bg[c] += 32;
        }
        {
            short8 af[4], bfr[4];
#pragma unroll
            for (int i = 0; i < 4; i++)
                af[i] = *(const short8*)&Al[0][(wm + i * 16 + l15) * 32 + quad * 8];
#pragma unroll
            for (int j = 0; j < 4; j++)
                bfr[j] = *(const short8*)&Bl[0][(wn + j * 16 + l15) * 32 + quad * 8];
#pragma unroll
            for (int i = 0; i < 4; i++)
#pragma unroll
                for (int j = 0; j < 4; j++) acc[i][j] = MFMA16(af[i], bfr[j], acc[i][j]);
        }
        asm volatile("s_waitcnt vmcnt(0)" ::: "memory");
        __syncthreads();

        if (kk < 15) {
#pragma unroll
            for (int c = 0; c < 2; c++) {
                load_lds16(ag[c], &Al[0][lofs[c]]);
                load_lds16(bg[c], &Bl[0][lofs[c]]);
                ag[c] += 32; bg[c] += 32;
            }
        }
        {
            short8 af[4], bfr[4];
#pragma unroll
            for (int i = 0; i < 4; i++)
                af[i] = *(const short8*)&Al[1][(wm + i * 16 + l15) * 32 + quad * 8];
#pragma unroll
            for (int j = 0; j < 4; j++)
                bfr[j] = *(const short8*)&Bl[1][(wn + j * 16 + l15) * 32 + quad * 8];
#pragma unroll
            for (int i = 0; i < 4; i++)
#pragma unroll
                for (int j = 0; j < 4; j++) acc[i][j] = MFMA16(af[i], bfr[j], acc[i][j]);
        }
        asm volatile("s_waitcnt vmcnt(0)" ::: "memory");
        __syncthreads();
    }

    bool out_f32 = (MODE == 0) ? sniff_f32(xsniff) : false;
#pragma unroll
    for (int i = 0; i < 4; i++) {
#pragma unroll
        for (int j = 0; j < 4; j++) {
            int col = n0 + wn + j * 16 + l15;
            int row0 = m0 + wm + i * 16 + quad * 4;
            if (MODE == 0) {
#pragma unroll
                for (int r = 0; r < 4; r++) {
                    size_t idx = (size_t)(row0 + r) * 1024 + col;
                    if (out_f32) ((float*)C0)[idx] = acc[i][j][r];
                    else ((unsigned short*)C0)[idx] = f2bf(acc[i][j][r]);
                }
            } else {
                int which = col >> 10, nn = col & 1023;  // uniform per block
                int b = row0 >> 11, s0 = row0 & 2047;
                if (which == 2) {
                    int hh = nn >> 6, d = nn & 63;
                    uint32_t lo = pkbf(acc[i][j][0], acc[i][j][1]);
                    uint32_t hi = pkbf(acc[i][j][2], acc[i][j][3]);
                    *(uint64_t*)(C2 + ((size_t)((b * 16 + hh) * 64 + d)) * 2048 + s0) =
                        (uint64_t)lo | ((uint64_t)hi << 32);
                } else {
                    int d = nn & 63;
                    unsigned short* dst = (which == 0) ? (unsigned short*)C0 : C1;
                    float sc = (which == 0) ? 0.18033688011112042f : 1.0f;  // 0.125*log2(e)
#pragma unroll
                    for (int r = 0; r < 4; r++) {
                        int s = s0 + r;
                        float v = acc[i][j][r];
                        float pv = __shfl_xor(v, 1);
                        float2 cs = tab[(s << 5) + (d >> 1)];
                        float o = (d & 1) ? (v * cs.x + pv * cs.y) : (v * cs.x - pv * cs.y);
                        dst[((size_t)(b * 2048 + s)) * 1024 + nn] = f2bf(o * sc);
                    }
                }
            }
        }
    }
}

// ---------------- flash attention v4: q-tile 128, 4 blocks/CU ----------------
// grid (64, 16): x = b*16+h; y -> q-tile (big-first; y and y+8 pair to 34 kt). Block 256 = 4 waves.
// Wave w owns q cols [qt*128+w*32, +32). K-tile 64, processed as 2x mb=32.
// S^T = K·Q^T via 32x32x16 MFMA; P^T assembled in-register; O^T = V^T·P^T.
__global__ __launch_bounds__(256, 4) void flash_k(
    const unsigned short* __restrict__ Qb,
    const unsigned short* __restrict__ Kb,
    const unsigned short* __restrict__ Vt,   // (B,H,64,S)
    unsigned short* __restrict__ A2) {
    __shared__ __align__(16) unsigned short Kl[2][64 * 64];  // [kv][d] swizzled
    __shared__ __align__(16) unsigned short Vl[2][64 * 64];  // [d][kv] swizzled

    int bh = blockIdx.x;
    int y = blockIdx.y;
    int qt = (y < 8) ? (15 - y) : (y - 8);  // big tiles first; y and y+8 pair to 34 kt
    int b = bh >> 4, h = bh & 15;
    int t = threadIdx.x, lane = t & 63, w = t >> 6;
    int l31 = lane & 31, half = lane >> 5;
    size_t base = ((size_t)b * 2048) * 1024 + h * 64;
    int q0w = qt * 128 + w * 32;

    // resident Q^T B-fragments [ks]
    short8 Qf[4];
#pragma unroll
    for (int ks = 0; ks < 4; ks++)
        Qf[ks] = *(const short8*)(Qb + base + (size_t)(q0w + l31) * 1024 + ks * 16 + half * 8);

    floatx16 O[2];
    O[0] = (floatx16)0.0f; O[1] = (floatx16)0.0f;
    float lsum = 0.f;

    int nk = 2 * (qt + 1);

    int srow = t >> 2;
    const unsigned short* kg = Kb + base + (size_t)srow * 1024 + (t & 3) * 16;
    const unsigned short* vg = Vt + ((size_t)(bh * 64 + srow)) * 2048 + (t & 3) * 16;
    int sw0 = srow * 64 + ((((t & 3) * 2 + 0) ^ (srow & 7)) * 8);
    int sw1 = srow * 64 + ((((t & 3) * 2 + 1) ^ (srow & 7)) * 8);

    short8 rk0 = *(const short8*)(kg);
    short8 rk1 = *(const short8*)(kg + 8);
    short8 rv0 = *(const short8*)(vg);
    short8 rv1 = *(const short8*)(vg + 8);

    for (int kt = 0; kt < nk; kt++) {
        int k0 = kt * 64, bf = kt & 1;
        *(short8*)&Kl[bf][sw0] = rk0;
        *(short8*)&Kl[bf][sw1] = rk1;
        *(short8*)&Vl[bf][sw0] = rv0;
        *(short8*)&Vl[bf][sw1] = rv1;
        __syncthreads();
        if (kt + 1 < nk) {
            size_t ko = (size_t)(kt + 1) * 64;
            rk0 = *(const short8*)(kg + ko * 1024);
            rk1 = *(const short8*)(kg + ko * 1024 + 8);
            rv0 = *(const short8*)(vg + ko);
            rv1 = *(const short8*)(vg + ko + 8);
        }
#pragma unroll
        for (int mb = 0; mb < 2; mb++) {
            if (k0 + mb * 32 >= q0w + 32) continue;  // fully-masked 32-row band
            short8 Ka[4];
#pragma unroll
            for (int ks = 0; ks < 4; ks++)
                Ka[ks] = *(const short8*)&Kl[bf][(mb * 32 + l31) * 64 +
                                                 (((ks * 2 + half) ^ (l31 & 7)) * 8)];
            floatx16 Sc = (floatx16)0.0f;
#pragma unroll
            for (int ks = 0; ks < 4; ks++)
                Sc = MFMA32(Ka[ks], Qf[ks], Sc);

            bool domask = (k0 + mb * 32 + 31 > q0w);
            float p[16];
#pragma unroll
            for (int e = 0; e < 16; e++) {
                float v = exp2f(Sc[e]);
                if (domask) {
                    int kv = k0 + mb * 32 + (e & 3) + ((e >> 2) << 3) + half * 4;
                    int qq = q0w + l31;
                    v = (kv > qq) ? 0.f : v;
                }
                p[e] = v;
            }
            float t0 = (p[0] + p[1]) + (p[2] + p[3]);
            float t1 = (p[4] + p[5]) + (p[6] + p[7]);
            float t2 = (p[8] + p[9]) + (p[10] + p[11]);
            float t3 = (p[12] + p[13]) + (p[14] + p[15]);
            lsum += (t0 + t1) + (t2 + t3);
            uint32_t pkm[8];
#pragma unroll
            for (int jj = 0; jj < 8; jj++)
                pkm[jj] = pkbf(p[2 * jj], p[2 * jj + 1]);

            short8 Va[2][2];  // [db][ks2]
#pragma unroll
            for (int db = 0; db < 2; db++)
#pragma unroll
                for (int ks2 = 0; ks2 < 2; ks2++)
                    Va[db][ks2] = *(const short8*)&Vl[bf][(db * 32 + l31) * 64 +
                                                         ((((mb * 2 + ks2) * 2 + half) ^ (l31 & 7)) * 8)];
#pragma unroll
            for (int ks2 = 0; ks2 < 2; ks2++) {
                uint32_t p0 = pkm[4 * ks2 + 0];
                uint32_t p1 = pkm[4 * ks2 + 1];
                uint32_t p2 = pkm[4 * ks2 + 2];
                uint32_t p3 = pkm[4 * ks2 + 3];
                uint32_t u = half ? p0 : p2;
                uint32_t v2 = half ? p1 : p3;
                uint32_t ya = (uint32_t)__shfl_xor((int)u, 32);
                uint32_t yb = (uint32_t)__shfl_xor((int)v2, 32);
                union { short8 s; uint32_t q[4]; } bb;
                bb.q[0] = half ? ya : p0;
                bb.q[1] = half ? yb : p1;
                bb.q[2] = half ? p2 : ya;
                bb.q[3] = half ? p3 : yb;
#pragma unroll
                for (int db = 0; db < 2; db++)
                    O[db] = MFMA32(Va[db][ks2], bb.s, O[db]);
            }
        }
    }

    float tot = lsum + __shfl_xor(lsum, 32);
    float inv = 1.0f / tot;
#pragma unroll
    for (int db = 0; db < 2; db++) {
        int scol = q0w + l31;
        unsigned short* op = A2 + base + (size_t)scol * 1024;
#pragma unroll
        for (int g = 0; g < 4; g++) {
            int d0 = db * 32 + half * 4 + g * 8;
            float v0 = O[db][g * 4 + 0] * inv;
            float v1 = O[db][g * 4 + 1] * inv;
            float v2 = O[db][g * 4 + 2] * inv;
            float v3 = O[db][g * 4 + 3] * inv;
            uint32_t lo = pkbf(v0, v1), hi = pkbf(v2, v3);
            *(uint64_t*)(op + d0) = (uint64_t)lo | ((uint64_t)hi << 32);
        }
    }
}

extern "C" void kernel_launch(void* const* d_in, const int* in_sizes, int n_in,
                              void* d_out, int out_size, void* d_ws, size_t ws_size,
                              hipStream_t stream) {
    const void* x  = d_in[0];
    const void* wq = d_in[1];
    const void* wk = d_in[2];
    const void* wv = d_in[3];
    const void* wo = d_in[4];

    char* ws = (char*)d_ws;
    unsigned short* WT  = (unsigned short*)(ws);                        // 3x1024x1024 bf16
    unsigned short* WoT = (unsigned short*)(ws + 6291456);              // 1024x1024 bf16
    float2*         tab = (float2*)(ws + 8388608);                      // 2048x32 float2
    unsigned short* xb  = (unsigned short*)(ws + 8913920);              // 16 MB bf16 x
    unsigned short* Qb  = (unsigned short*)(ws + 8913920 + 16777216ull);
    unsigned short* Kb  = (unsigned short*)(ws + 8913920 + 2ull * 16777216);
    unsigned short* Vt  = (unsigned short*)(ws + 8913920 + 3ull * 16777216);  // (B,H,64,S)
    unsigned short* A2  = xb;  // alias: xb dead after QKV GEMM

    prep_k<<<8448, 256, 0, stream>>>(x, wq, wk, wv, wo, WT, WoT, tab, xb);

    gemm_bt<1><<<dim3(24, 64), 256, 0, stream>>>(xb, WT, Qb, Kb, Vt, tab,
                                                 (const unsigned short*)x);
    flash_k<<<dim3(64, 16), 256, 0, stream>>>(Qb, Kb, Vt, A2);
    gemm_bt<0><<<dim3(8, 64), 256, 0, stream>>>(A2, WoT, d_out, nullptr, nullptr, tab,
                                                (const unsigned short*)x);
}